// Round 13
// baseline (663.509 us; speedup 1.0000x reference)
//
#include <hip/hip_runtime.h>

// LocallyConnectedLayer: out[b,o,i,j] = sum_{c,u,v} x[b,c,i+u,j+v] * w[o,c,i,j,u,v] + bias[o,i,j]
// x: (32,32,64,64) f32, w: (64,32,62,62,3,3) f32, bias: (64,62,62) f32, out: (32,64,62,62) f32
//
// R7 post-mortem: stride-36B weight gathers (35 lines/wave-load) x 4-wave duplication
// = ~620k TCP line-txn cycles/CU, plus residual scratch spill (WRITE 332 MB). Fix:
//  - per c, wave wv stages the w panel for o=ob+wv into LDS (3 loads = exactly 36 B/lane),
//    LDS records padded 9->12 floats so ds accesses are 16B-aligned & bank-conflict-free.
//  - each wave register-hoists 4o x 9 w via 12 vector ds_reads, then FMAs 8 batches.
//  - x: one unaligned dwordx4 per (b,row) covering cols j..j+2 (clamped at j=0, cndmask
//    selects) -> 24 x-loads/wave/c, no OOB at either buffer edge.
//  - double-buffered LDS, T14 split: issue stage loads -> compute -> ds_write -> barrier.

#define B_  32
#define C_  32
#define O_  64
#define H_  64
#define W_  64
#define K_  3
#define OH_ 62
#define OW_ 62

#define OSTR  (C_ * OH_ * OW_ * K_ * K_)   // 1,107,072
#define CSTRW (OH_ * OW_ * K_ * K_)        //    34,596
#define BSTRX (C_ * H_ * W_)               //   131,072
#define CSTRX (H_ * W_)                    //     4,096

typedef float f4 __attribute__((ext_vector_type(4)));

__global__ __launch_bounds__(256, 4)
void lcl_fwd(const float* __restrict__ x, const float* __restrict__ w,
             const float* __restrict__ bias, float* __restrict__ out) {
    // double-buffered weight panel: [buf][o][j][12] floats (record padded 9->12)
    __shared__ float wlds[2][4][OW_][12];

    const int j  = threadIdx.x & 63;     // lane spans output column
    const int wv = threadIdx.x >> 6;     // wave id: stages o=ob+wv, computes batches b0..b0+7
    const int i  = blockIdx.y;           // output row
    const int ob = blockIdx.x * 4;       // this block's 4 output channels
    const int b0 = wv * 8;
    const bool act = (j < OW_);          // lanes 62,63 idle (wave still reaches barriers)

    float acc[8][4];
#pragma unroll
    for (int b = 0; b < 8; ++b)
#pragma unroll
        for (int o = 0; o < 4; ++o) acc[b][o] = 0.0f;

    // this thread's weight record (o=ob+wv, c=0, i, j): 9 contiguous floats
    const float* wrec0 = w + ((size_t)((ob + wv) * C_) * OH_ + i) * OW_ * 9 + (size_t)j * 9;
    // clamped start column for the x dwordx4 (covers cols j..j+2 with no OOB)
    const int jm1 = (j == 0) ? 0 : (j - 1);

    // ---------- prologue: stage c=0 ----------
    if (act) {
        const float* p = wrec0;
        f4 a, b;
        __builtin_memcpy(&a, p, 16);
        __builtin_memcpy(&b, p + 4, 16);
        *(f4*)&wlds[0][wv][j][0] = a;
        *(f4*)&wlds[0][wv][j][4] = b;
        wlds[0][wv][j][8] = p[8];
    }
    __syncthreads();

    for (int c = 0; c < C_; ++c) {
        const int cur = c & 1;
        const bool st = act && (c + 1 < C_);

        // ---- issue next panel's global loads early (T14: latency hides under compute)
        f4 sa, sb; float sc8 = 0.0f;
        if (st) {
            const float* p = wrec0 + (size_t)(c + 1) * CSTRW;
            __builtin_memcpy(&sa, p, 16);
            __builtin_memcpy(&sb, p + 4, 16);
            sc8 = p[8];
        }

        if (act) {
            // ---- hoist w for all 4 o's from LDS into registers (12 vector ds_reads)
            float wt[4][9];
#pragma unroll
            for (int o = 0; o < 4; ++o) {
                f4 a = *(const f4*)&wlds[cur][o][j][0];
                f4 b = *(const f4*)&wlds[cur][o][j][4];
                wt[o][0] = a.x; wt[o][1] = a.y; wt[o][2] = a.z; wt[o][3] = a.w;
                wt[o][4] = b.x; wt[o][5] = b.y; wt[o][6] = b.z; wt[o][7] = b.w;
                wt[o][8] = wlds[cur][o][j][8];
            }

            // ---- x loads + FMAs: 8 batches x 3 rows, one dwordx4 each
            const float* xrow0 = x + ((size_t)(b0 * C_ + c) * CSTRX) + (size_t)i * W_ + jm1;
#pragma unroll
            for (int b = 0; b < 8; ++b) {
                const float* xb = xrow0 + (size_t)b * BSTRX;
#pragma unroll
                for (int u = 0; u < K_; ++u) {
                    f4 xr;
                    __builtin_memcpy(&xr, xb + u * W_, 16);
                    const float x0 = (j == 0) ? xr.x : xr.y;  // col j
                    const float x1 = (j == 0) ? xr.y : xr.z;  // col j+1
                    const float x2 = (j == 0) ? xr.z : xr.w;  // col j+2
#pragma unroll
                    for (int o = 0; o < 4; ++o) {
                        acc[b][o] = fmaf(x0, wt[o][u * 3 + 0], acc[b][o]);
                        acc[b][o] = fmaf(x1, wt[o][u * 3 + 1], acc[b][o]);
                        acc[b][o] = fmaf(x2, wt[o][u * 3 + 2], acc[b][o]);
                    }
                }
            }
        }

        // ---- write staged panel for c+1 into the other buffer, then one barrier
        if (st) {
            const int nxt = cur ^ 1;
            *(f4*)&wlds[nxt][wv][j][0] = sa;
            *(f4*)&wlds[nxt][wv][j][4] = sb;
            wlds[nxt][wv][j][8] = sc8;
        }
        __syncthreads();
    }

    // ---------- epilogue: bias + coalesced store ----------
    if (act) {
        const int pos = i * OW_ + j;
        float bz[4];
#pragma unroll
        for (int o = 0; o < 4; ++o) bz[o] = bias[(ob + o) * (OH_ * OW_) + pos];

#pragma unroll
        for (int b = 0; b < 8; ++b) {
#pragma unroll
            for (int o = 0; o < 4; ++o) {
                out[(((size_t)(b0 + b) * O_ + (ob + o)) * OH_ + i) * OW_ + j] = acc[b][o] + bz[o];
            }
        }
    }
}

extern "C" void kernel_launch(void* const* d_in, const int* in_sizes, int n_in,
                              void* d_out, int out_size, void* d_ws, size_t ws_size,
                              hipStream_t stream) {
    const float* x    = (const float*)d_in[0];
    const float* w    = (const float*)d_in[1];
    const float* bias = (const float*)d_in[2];
    float* out = (float*)d_out;

    dim3 grid(O_ / 4, OH_);   // (16, 62) = 992 blocks
    dim3 block(256);          // 4 waves
    lcl_fwd<<<grid, block, 0, stream>>>(x, w, bias, out);
}

// Round 14
// 595.483 us; speedup vs baseline: 1.1142x; 1.1142x over previous
//
#include <hip/hip_runtime.h>

// LocallyConnectedLayer: out[b,o,i,j] = sum_{c,u,v} x[b,c,i+u,j+v] * w[o,c,i,j,u,v] + bias[o,i,j]
// x: (32,32,64,64) f32, w: (64,32,62,62,3,3) f32, bias: (64,62,62) f32, out: (32,64,62,62) f32
//
// R13 post-mortem: structure right (FETCH fixed, LDS staging live) but VGPR_Count=64
// forced ~30-reg spill -> WRITE 143 MB (110 MB scratch) and 383 us. Cause:
// __launch_bounds__(256,4) capped the allocator (4 waves/SIMD -> <=128, halved to 64).
// Fix: __launch_bounds__(256,2) -> cap 256; per-thread demand ~95 regs fits w/o spill.
//  - per c, wave wv stages the w panel for o=ob+wv into LDS (36 B/lane),
//    records padded 9->12 floats: 16B-aligned ds_read_b128, stride-48B = conflict-free.
//  - each wave register-hoists 4o x 9 w via 12 vector ds_reads, then FMAs 8 batches.
//  - x: one unaligned dwordx4 per (b,row) covering cols j..j+2 (clamped at j=0).
//  - double-buffered LDS, issue-early/write-late staging, one barrier per c.

#define B_  32
#define C_  32
#define O_  64
#define H_  64
#define W_  64
#define K_  3
#define OH_ 62
#define OW_ 62

#define OSTR  (C_ * OH_ * OW_ * K_ * K_)   // 1,107,072
#define CSTRW (OH_ * OW_ * K_ * K_)        //    34,596
#define BSTRX (C_ * H_ * W_)               //   131,072
#define CSTRX (H_ * W_)                    //     4,096

typedef float f4 __attribute__((ext_vector_type(4)));

__global__ __launch_bounds__(256, 2)
void lcl_fwd(const float* __restrict__ x, const float* __restrict__ w,
             const float* __restrict__ bias, float* __restrict__ out) {
    // double-buffered weight panel: [buf][o][j][12] floats (record padded 9->12)
    __shared__ float wlds[2][4][OW_][12];

    const int j  = threadIdx.x & 63;     // lane spans output column
    const int wv = threadIdx.x >> 6;     // wave id: stages o=ob+wv, computes batches b0..b0+7
    const int i  = blockIdx.y;           // output row
    const int ob = blockIdx.x * 4;       // this block's 4 output channels
    const int b0 = wv * 8;
    const bool act = (j < OW_);          // lanes 62,63 idle (wave still reaches barriers)

    float acc[8][4];
#pragma unroll
    for (int b = 0; b < 8; ++b)
#pragma unroll
        for (int o = 0; o < 4; ++o) acc[b][o] = 0.0f;

    // this thread's weight record (o=ob+wv, c=0, i, j): 9 contiguous floats
    const float* wrec0 = w + ((size_t)((ob + wv) * C_) * OH_ + i) * OW_ * 9 + (size_t)j * 9;
    // clamped start column for the x dwordx4 (covers cols j..j+2 with no OOB)
    const int jm1 = (j == 0) ? 0 : (j - 1);

    // ---------- prologue: stage c=0 ----------
    if (act) {
        const float* p = wrec0;
        f4 a, b;
        __builtin_memcpy(&a, p, 16);
        __builtin_memcpy(&b, p + 4, 16);
        *(f4*)&wlds[0][wv][j][0] = a;
        *(f4*)&wlds[0][wv][j][4] = b;
        wlds[0][wv][j][8] = p[8];
    }
    __syncthreads();

    for (int c = 0; c < C_; ++c) {
        const int cur = c & 1;
        const bool st = act && (c + 1 < C_);

        // ---- issue next panel's global loads early (latency hides under compute)
        f4 sa, sb; float sc8 = 0.0f;
        if (st) {
            const float* p = wrec0 + (size_t)(c + 1) * CSTRW;
            __builtin_memcpy(&sa, p, 16);
            __builtin_memcpy(&sb, p + 4, 16);
            sc8 = p[8];
        }

        if (act) {
            // ---- hoist w for all 4 o's from LDS into registers (12 vector ds_reads)
            float wt[4][9];
#pragma unroll
            for (int o = 0; o < 4; ++o) {
                f4 a = *(const f4*)&wlds[cur][o][j][0];
                f4 b = *(const f4*)&wlds[cur][o][j][4];
                wt[o][0] = a.x; wt[o][1] = a.y; wt[o][2] = a.z; wt[o][3] = a.w;
                wt[o][4] = b.x; wt[o][5] = b.y; wt[o][6] = b.z; wt[o][7] = b.w;
                wt[o][8] = wlds[cur][o][j][8];
            }

            // ---- x loads + FMAs: 8 batches x 3 rows, one dwordx4 each
            const float* xrow0 = x + ((size_t)(b0 * C_ + c) * CSTRX) + (size_t)i * W_ + jm1;
#pragma unroll
            for (int b = 0; b < 8; ++b) {
                const float* xb = xrow0 + (size_t)b * BSTRX;
#pragma unroll
                for (int u = 0; u < K_; ++u) {
                    f4 xr;
                    __builtin_memcpy(&xr, xb + u * W_, 16);
                    const float x0 = (j == 0) ? xr.x : xr.y;  // col j
                    const float x1 = (j == 0) ? xr.y : xr.z;  // col j+1
                    const float x2 = (j == 0) ? xr.z : xr.w;  // col j+2
#pragma unroll
                    for (int o = 0; o < 4; ++o) {
                        acc[b][o] = fmaf(x0, wt[o][u * 3 + 0], acc[b][o]);
                        acc[b][o] = fmaf(x1, wt[o][u * 3 + 1], acc[b][o]);
                        acc[b][o] = fmaf(x2, wt[o][u * 3 + 2], acc[b][o]);
                    }
                }
            }
        }

        // ---- write staged panel for c+1 into the other buffer, then one barrier
        if (st) {
            const int nxt = cur ^ 1;
            *(f4*)&wlds[nxt][wv][j][0] = sa;
            *(f4*)&wlds[nxt][wv][j][4] = sb;
            wlds[nxt][wv][j][8] = sc8;
        }
        __syncthreads();
    }

    // ---------- epilogue: bias + coalesced store ----------
    if (act) {
        const int pos = i * OW_ + j;
        float bz[4];
#pragma unroll
        for (int o = 0; o < 4; ++o) bz[o] = bias[(ob + o) * (OH_ * OW_) + pos];

#pragma unroll
        for (int b = 0; b < 8; ++b) {
#pragma unroll
            for (int o = 0; o < 4; ++o) {
                out[(((size_t)(b0 + b) * O_ + (ob + o)) * OH_ + i) * OW_ + j] = acc[b][o] + bz[o];
            }
        }
    }
}

extern "C" void kernel_launch(void* const* d_in, const int* in_sizes, int n_in,
                              void* d_out, int out_size, void* d_ws, size_t ws_size,
                              hipStream_t stream) {
    const float* x    = (const float*)d_in[0];
    const float* w    = (const float*)d_in[1];
    const float* bias = (const float*)d_in[2];
    float* out = (float*)d_out;

    dim3 grid(O_ / 4, OH_);   // (16, 62) = 992 blocks
    dim3 block(256);          // 4 waves
    lcl_fwd<<<grid, block, 0, stream>>>(x, w, bias, out);
}

// Round 16
// 484.605 us; speedup vs baseline: 1.3692x; 1.2288x over previous
//
#include <hip/hip_runtime.h>

// LocallyConnectedLayer: out[b,o,i,j] = sum_{c,u,v} x[b,c,i+u,j+v] * w[o,c,i,j,u,v] + bias[o,i,j]
// x: (32,32,64,64) f32, w: (64,32,62,62,3,3) f32, bias: (64,62,62) f32, out: (32,64,62,62) f32
//
// R14 post-mortem: spill fixed (WRITE 30.8 MB) but latency-bound: 317 us with HBM 9.6%,
// VALU 17.6%, occupancy 25% (2 blocks x 4 waves/CU), VALU-busy ~56 us = real work.
// Fixes this round:
//  - 512-thread blocks: 8 waves x 4 batches (acc[4][4]) -> ~31 waves/CU (4 blocks),
//    ~4x latency hiding, same grid and same HBM traffic (only waves 0..3 stage w).
//  - SoA tap-major w-LDS [o][tap][j]: lane-consecutive ds_write/ds_read -> zero bank
//    conflicts (R14 measured 3.8M conflict cycles from 12-float records, stride 12 mod 32).
//  - x unchanged: aligned-clamped dwordx4 per (b,row), selects hoisted per (b,u).

#define B_  32
#define C_  32
#define O_  64
#define H_  64
#define W_  64
#define K_  3
#define OH_ 62
#define OW_ 62

#define CSTRW (OH_ * OW_ * K_ * K_)        //    34,596
#define BSTRX (C_ * H_ * W_)               //   131,072
#define CSTRX (H_ * W_)                    //     4,096

typedef float f4 __attribute__((ext_vector_type(4)));

__global__ __launch_bounds__(512, 2)
void lcl_fwd(const float* __restrict__ x, const float* __restrict__ w,
             const float* __restrict__ bias, float* __restrict__ out) {
    // double-buffered weight panel, SoA tap-major: [buf][o][tap][j] (j padded 62->64)
    __shared__ float wlds[2][4][9][64];

    const int j  = threadIdx.x & 63;     // lane spans output column
    const int wv = threadIdx.x >> 6;     // wave id 0..7
    const int i  = blockIdx.y;           // output row
    const int ob = blockIdx.x * 4;       // this block's 4 output channels
    const int b0 = wv * 4;               // 4 batches per wave
    const bool act = (j < OW_);
    const bool stg = act && (wv < 4);    // waves 0..3 stage panel o = wv

    float acc[4][4];
#pragma unroll
    for (int b = 0; b < 4; ++b)
#pragma unroll
        for (int o = 0; o < 4; ++o) acc[b][o] = 0.0f;

    // stager's weight record (o=ob+wv, c, i, j): 9 contiguous floats
    const float* wrec0 = w + ((size_t)((ob + (wv & 3)) * C_) * OH_ + i) * OW_ * 9 + (size_t)j * 9;
    // clamped start col for x dwordx4 covering cols j..j+2 (no OOB at either edge)
    const int jm1 = (j == 0) ? 0 : (j - 1);

    // ---------- prologue: stage c=0 ----------
    if (stg) {
        const float* p = wrec0;
        f4 a, b;
        __builtin_memcpy(&a, p, 16);
        __builtin_memcpy(&b, p + 4, 16);
        wlds[0][wv][0][j] = a.x; wlds[0][wv][1][j] = a.y;
        wlds[0][wv][2][j] = a.z; wlds[0][wv][3][j] = a.w;
        wlds[0][wv][4][j] = b.x; wlds[0][wv][5][j] = b.y;
        wlds[0][wv][6][j] = b.z; wlds[0][wv][7][j] = b.w;
        wlds[0][wv][8][j] = p[8];
    }
    __syncthreads();

    for (int c = 0; c < C_; ++c) {
        const int cur = c & 1;
        const bool st = stg && (c + 1 < C_);

        // ---- issue next panel's global loads early (latency hides under compute)
        f4 sa, sb; float sc8 = 0.0f;
        if (st) {
            const float* p = wrec0 + (size_t)(c + 1) * CSTRW;
            __builtin_memcpy(&sa, p, 16);
            __builtin_memcpy(&sb, p + 4, 16);
            sc8 = p[8];
        }

        if (act) {
            // ---- hoist w for 4 o's from LDS (36 lane-consecutive b32 reads, conflict-free)
            float wt[4][9];
#pragma unroll
            for (int o = 0; o < 4; ++o)
#pragma unroll
                for (int t = 0; t < 9; ++t) wt[o][t] = wlds[cur][o][t][j];

            // ---- x loads + FMAs: 4 batches x 3 rows, one dwordx4 each
            const float* xrow0 = x + ((size_t)(b0 * C_ + c) * CSTRX) + (size_t)i * W_ + jm1;
#pragma unroll
            for (int b = 0; b < 4; ++b) {
                const float* xb = xrow0 + (size_t)b * BSTRX;
#pragma unroll
                for (int u = 0; u < 3; ++u) {
                    f4 xr;
                    __builtin_memcpy(&xr, xb + u * W_, 16);
                    const float x0 = (j == 0) ? xr.x : xr.y;  // col j
                    const float x1 = (j == 0) ? xr.y : xr.z;  // col j+1
                    const float x2 = (j == 0) ? xr.z : xr.w;  // col j+2
#pragma unroll
                    for (int o = 0; o < 4; ++o) {
                        acc[b][o] = fmaf(x0, wt[o][u * 3 + 0], acc[b][o]);
                        acc[b][o] = fmaf(x1, wt[o][u * 3 + 1], acc[b][o]);
                        acc[b][o] = fmaf(x2, wt[o][u * 3 + 2], acc[b][o]);
                    }
                }
            }
        }

        // ---- write staged panel for c+1 into the other buffer, then one barrier
        if (st) {
            const int nxt = cur ^ 1;
            wlds[nxt][wv][0][j] = sa.x; wlds[nxt][wv][1][j] = sa.y;
            wlds[nxt][wv][2][j] = sa.z; wlds[nxt][wv][3][j] = sa.w;
            wlds[nxt][wv][4][j] = sb.x; wlds[nxt][wv][5][j] = sb.y;
            wlds[nxt][wv][6][j] = sb.z; wlds[nxt][wv][7][j] = sb.w;
            wlds[nxt][wv][8][j] = sc8;
        }
        __syncthreads();
    }

    // ---------- epilogue: bias + coalesced store ----------
    if (act) {
        const int pos = i * OW_ + j;
        float bz[4];
#pragma unroll
        for (int o = 0; o < 4; ++o) bz[o] = bias[(ob + o) * (OH_ * OW_) + pos];

#pragma unroll
        for (int b = 0; b < 4; ++b) {
#pragma unroll
            for (int o = 0; o < 4; ++o) {
                out[(((size_t)(b0 + b) * O_ + (ob + o)) * OH_ + i) * OW_ + j] = acc[b][o] + bz[o];
            }
        }
    }
}

extern "C" void kernel_launch(void* const* d_in, const int* in_sizes, int n_in,
                              void* d_out, int out_size, void* d_ws, size_t ws_size,
                              hipStream_t stream) {
    const float* x    = (const float*)d_in[0];
    const float* w    = (const float*)d_in[1];
    const float* bias = (const float*)d_in[2];
    float* out = (float*)d_out;

    dim3 grid(O_ / 4, OH_);   // (16, 62) = 992 blocks
    dim3 block(512);          // 8 waves = 8 batch groups of 4
    lcl_fwd<<<grid, block, 0, stream>>>(x, w, bias, out);
}